// Round 4
// baseline (515.312 us; speedup 1.0000x reference)
//
#include <hip/hip_runtime.h>

// MoE Router (Switch) — R8: bf16-split MFMA, barrier-free K-loop.
// logits = x@W + b; top-3 one-hot mask; softmax probs; importance = load = col-sum.
// x: [N=32768, D=2048] f32, W: [D, E=64] f32, b: [E] f32.
// out = [mask (N*E) | prob (N*E) | importance (E) | load (E)]  (f32)
//
// R7 post-mortem: all VALU formulations are LDS-pipe-bound (18 b128/kk4 vs
// 128 FMA -> VALUBusy pinned ~25%). HBM floor is 43 us; only MFMA gets there.
// Design:
//   * wprep: W -> 3 transposed bf16 planes Wt_p[64][2048] (h+m+l split) in ws.
//   * fused: 256 thr / 4 waves / 64 rows per block, grid 512.
//       wave owns 16 rows; A = x loaded DIRECT from global (f32) -> in-reg
//       3-way bf16 split; B = plane fragments loaded direct from global
//       (L2-resident). Six MFMA terms per e-tile: h1(g1,g2,g3)+h2(g1,g2)+h3 g1
//       => dropped terms <= 2^-24 -> logit error ~1e-6 (f32 class; top-3
//       tie-break safe). NO LDS, NO barriers in the K-loop; 2-stage register
//       pipeline.
//     k-mapping: element i of lane-group g <-> k = 8g + i in BOTH A and B
//     (operand layouts are lane-symmetric -> correct for any HW k-perm).
//     C/D layout (HW-verified): col = lane&15, row = 4*(lane>>4) + reg.
//   * epilogue: logits->LDS once; R5-VERIFIED top3/merge12/softmax with
//     lane=row, quarter=wave; coalesced output via LDS bounce.

#define D_MODEL 2048
#define N_EXP   64
#define BK      32
#define NCH     (D_MODEL / BK)   // 64
#define ROWS    64               // rows per block
#define NBLK    512              // 32768 / 64
#define LPITCH  68               // padded LDS row pitch (16B-aligned)

typedef short bf16x8 __attribute__((ext_vector_type(8)));
typedef float f32x4  __attribute__((ext_vector_type(4)));

__device__ __forceinline__ unsigned short f32_bf16(float f) {
    unsigned u = __float_as_uint(f);
    return (unsigned short)((u + 0x7FFFu + ((u >> 16) & 1u)) >> 16);  // RNE
}
__device__ __forceinline__ float bf16_f32(unsigned short h) {
    return __uint_as_float((unsigned)h << 16);
}

// ---- W prep: split + transpose -> Wt_p[64][2048] bf16, p = 0,1,2 ----
__global__ __launch_bounds__(256) void wprep_kernel(
    const float* __restrict__ W, unsigned short* __restrict__ wt) {
    const int gid = blockIdx.x * 256 + threadIdx.x;   // 32768 threads
    const int k   = gid & (D_MODEL - 1);
    const int e4  = gid >> 11;                        // 0..15
    const float4 w = *(const float4*)(W + (size_t)k * N_EXP + e4 * 4);
    unsigned short* p1 = wt;
    unsigned short* p2 = wt + (size_t)N_EXP * D_MODEL;
    unsigned short* p3 = wt + (size_t)2 * N_EXP * D_MODEL;
#pragma unroll
    for (int j = 0; j < 4; ++j) {
        const float xv = ((const float*)&w)[j];
        const unsigned short h1 = f32_bf16(xv); const float f1 = bf16_f32(h1);
        const float r1 = xv - f1;
        const unsigned short h2 = f32_bf16(r1); const float f2 = bf16_f32(h2);
        const unsigned short h3 = f32_bf16(r1 - f2);
        const size_t o = (size_t)(e4 * 4 + j) * D_MODEL + k;  // transposed
        p1[o] = h1; p2[o] = h2; p3[o] = h3;
    }
}

// ---- fused: GEMM (MFMA) + top-3 + softmax + partial col-sums ----
__global__ __launch_bounds__(256, 2) void fused_kernel(
    const float* __restrict__ x, const unsigned short* __restrict__ wt,
    const float* __restrict__ b,
    float* __restrict__ out_mask, float* __restrict__ out_prob,
    float* __restrict__ pws) {

    __shared__ float lgt[ROWS * LPITCH];   // logits, later probs
    __shared__ float msk[ROWS * LPITCH];   // mask bounce
    __shared__ float cnd[4 * ROWS * 8];    // top-3 candidates
    __shared__ float ess[4 * ROWS];        // exp partial sums

    const int tid  = threadIdx.x;
    const int lane = tid & 63;
    const int wv   = tid >> 6;        // 0..3
    const int n    = lane & 15;       // A row-in-tile / B expert-in-tile
    const int g    = lane >> 4;       // k-group
    const int rg   = blockIdx.x;
    const int row0 = rg * ROWS + wv * 16;

    // A: x[row0 + n][c*32 + 8g + i], i = 0..7 (two float4)
    const float* ap = x + (size_t)(row0 + n) * D_MODEL + 8 * g;

    // B: Wt_p[16t + n][c*32 + 8g + i] (contiguous 8 bf16 = one dwordx4)
    const unsigned short* bp[4][3];
#pragma unroll
    for (int t = 0; t < 4; ++t) {
        const size_t ro = (size_t)(16 * t + n) * D_MODEL + 8 * g;
#pragma unroll
        for (int p = 0; p < 3; ++p)
            bp[t][p] = wt + (size_t)p * ((size_t)N_EXP * D_MODEL) + ro;
    }

    f32x4 acc[4];
#pragma unroll
    for (int t = 0; t < 4; ++t)
#pragma unroll
        for (int j = 0; j < 4; ++j) acc[t][j] = 0.0f;

    auto LOAD = [&](float4& s0, float4& s1, bf16x8* sb, int c) {
        s0 = *(const float4*)(ap + c * BK);
        s1 = *(const float4*)(ap + c * BK + 4);
#pragma unroll
        for (int t = 0; t < 4; ++t)
#pragma unroll
            for (int p = 0; p < 3; ++p)
                sb[t * 3 + p] = *(const bf16x8*)(bp[t][p] + c * BK);
    };

    auto COMPUTE = [&](const float4& s0, const float4& s1, const bf16x8* sb) {
        bf16x8 h1, h2, h3;
#pragma unroll
        for (int i = 0; i < 8; ++i) {
            const float xv = (i < 4) ? ((const float*)&s0)[i]
                                     : ((const float*)&s1)[i - 4];
            const unsigned short a1 = f32_bf16(xv); const float f1 = bf16_f32(a1);
            const float r1 = xv - f1;
            const unsigned short a2 = f32_bf16(r1); const float f2 = bf16_f32(a2);
            const unsigned short a3 = f32_bf16(r1 - f2);
            h1[i] = (short)a1; h2[i] = (short)a2; h3[i] = (short)a3;
        }
#pragma unroll
        for (int t = 0; t < 4; ++t) {
            acc[t] = __builtin_amdgcn_mfma_f32_16x16x32_bf16(h1, sb[t*3+0], acc[t], 0, 0, 0);
            acc[t] = __builtin_amdgcn_mfma_f32_16x16x32_bf16(h1, sb[t*3+1], acc[t], 0, 0, 0);
            acc[t] = __builtin_amdgcn_mfma_f32_16x16x32_bf16(h1, sb[t*3+2], acc[t], 0, 0, 0);
            acc[t] = __builtin_amdgcn_mfma_f32_16x16x32_bf16(h2, sb[t*3+0], acc[t], 0, 0, 0);
            acc[t] = __builtin_amdgcn_mfma_f32_16x16x32_bf16(h2, sb[t*3+1], acc[t], 0, 0, 0);
            acc[t] = __builtin_amdgcn_mfma_f32_16x16x32_bf16(h3, sb[t*3+0], acc[t], 0, 0, 0);
        }
    };

    float4 a0A, a1A, a0B, a1B;
    bf16x8 bA[12], bB[12];

    LOAD(a0A, a1A, bA, 0);
    for (int c = 0; c < NCH; c += 2) {
        LOAD(a0B, a1B, bB, c + 1);
        COMPUTE(a0A, a1A, bA);
        if (c + 2 < NCH) LOAD(a0A, a1A, bA, c + 2);
        COMPUTE(a0B, a1B, bB);
    }

    // ---- logits (+bias) -> LDS ----
    float bt[4];
#pragma unroll
    for (int t = 0; t < 4; ++t) bt[t] = b[16 * t + n];
#pragma unroll
    for (int t = 0; t < 4; ++t)
#pragma unroll
        for (int j = 0; j < 4; ++j)
            lgt[(wv * 16 + 4 * g + j) * LPITCH + 16 * t + n] = acc[t][j] + bt[t];

    __syncthreads();

    // ---- epilogue: quarter q = wv, lane = row [R5-verified logic] ----
    const int q   = wv;
    const int row = lane;
    const int e0q = 16 * q;

    float v[16];
#pragma unroll
    for (int i = 0; i < 16; ++i) v[i] = lgt[row * LPITCH + e0q + i];

    {   // per-lane top-3 of 16 (ascending scan, strict > = lowest-index ties)
        float t1 = -INFINITY, t2 = -INFINITY, t3 = -INFINITY;
        int   j1 = 0, j2 = 0, j3 = 0;
#pragma unroll
        for (int e = 0; e < 16; ++e) {
            const float xv = v[e]; const int ge = e0q + e;
            if (xv > t1)      { t3 = t2; j3 = j2; t2 = t1; j2 = j1; t1 = xv; j1 = ge; }
            else if (xv > t2) { t3 = t2; j3 = j2; t2 = xv; j2 = ge; }
            else if (xv > t3) { t3 = xv; j3 = ge; }
        }
        float* cp = &cnd[(q * ROWS + row) * 8];
        cp[0] = t1; cp[1] = __int_as_float(j1);
        cp[2] = t2; cp[3] = __int_as_float(j2);
        cp[4] = t3; cp[5] = __int_as_float(j3);
    }
    __syncthreads();

    float x1 = 0.0f; int i1 = -1, i2 = -1, i3 = -1;
    {   // merge 4 quarters x 3 candidates (quarter-ascending = e-ascending)
        float bv[12]; int bg[12];
#pragma unroll
        for (int w = 0; w < 4; ++w) {
            const float* cp = &cnd[(w * ROWS + row) * 8];
#pragma unroll
            for (int k = 0; k < 3; ++k) {
                bv[w * 3 + k] = cp[2 * k];
                bg[w * 3 + k] = __float_as_int(cp[2 * k + 1]);
            }
        }
#pragma unroll
        for (int pick = 0; pick < 3; ++pick) {
            float mv = bv[0]; int mg = bg[0]; int mk = 0;
#pragma unroll
            for (int k = 1; k < 12; ++k)
                if (bv[k] > mv) { mv = bv[k]; mg = bg[k]; mk = k; }
            if (pick == 0)      { x1 = mv; i1 = mg; }
            else if (pick == 1) { i2 = mg; }
            else                { i3 = mg; }
#pragma unroll
            for (int k = 0; k < 12; ++k)
                if (k == mk) bv[k] = -INFINITY;   // static index: stays in regs
        }
    }

    float pe[16]; float es = 0.0f;
#pragma unroll
    for (int i = 0; i < 16; ++i) { pe[i] = __expf(v[i] - x1); es += pe[i]; }
    ess[q * ROWS + row] = es;
    __syncthreads();

    const float sinv = 1.0f / (ess[row] + ess[ROWS + row]
                             + ess[2 * ROWS + row] + ess[3 * ROWS + row]);
    float pr[16];
#pragma unroll
    for (int i = 0; i < 16; ++i) pr[i] = pe[i] * sinv;

    // probs overwrite lgt; mask into msk (all lgt reads completed)
#pragma unroll
    for (int i = 0; i < 16; ++i) {
        const int ge = e0q + i;
        lgt[row * LPITCH + ge - 0] = pr[i];
        msk[row * LPITCH + ge - 0] =
            (ge == i1 || ge == i2 || ge == i3) ? 1.0f : 0.0f;
    }

    // once-per-block column sums (importance/load partials) [R5-verified]
    float colAcc = 0.0f;
#pragma unroll
    for (int e = 0; e < 16; ++e) {
        float se = pr[e];
#pragma unroll
        for (int m = 32; m > 0; m >>= 1) se += __shfl_xor(se, m);
        colAcc = (lane == e) ? se : colAcc;       // static index per iter
    }
    if (lane < 16)
        pws[(size_t)(e0q + lane) * NBLK + rg] = colAcc;

    __syncthreads();

    // ---- coalesced stores via LDS bounce: 1024 float4 per array ----
    const size_t obase = (size_t)rg * (ROWS * N_EXP);
#pragma unroll
    for (int u = 0; u < 4; ++u) {
        const int f  = tid + u * 256;       // 0..1023
        const int r  = f >> 4;
        const int c4 = f & 15;
        *(float4*)(out_prob + obase + (size_t)f * 4) =
            *(const float4*)&lgt[r * LPITCH + c4 * 4];
        *(float4*)(out_mask + obase + (size_t)f * 4) =
            *(const float4*)&msk[r * LPITCH + c4 * 4];
    }
}

// one block per expert: sum its NBLK contiguous partials -> imp[e], load[e]
__global__ __launch_bounds__(256) void reduce_kernel(
    const float* __restrict__ pws,
    float* __restrict__ out_imp, float* __restrict__ out_load) {

    __shared__ float red[4];
    const int e   = blockIdx.x;
    const int tid = threadIdx.x;

    float s = pws[(size_t)e * NBLK + tid] + pws[(size_t)e * NBLK + tid + 256];

#pragma unroll
    for (int m = 32; m > 0; m >>= 1) s += __shfl_xor(s, m);
    if ((tid & 63) == 0) red[tid >> 6] = s;
    __syncthreads();
    if (tid == 0) {
        const float t = red[0] + red[1] + red[2] + red[3];
        out_imp[e]  = t;
        out_load[e] = t;
    }
}

extern "C" void kernel_launch(void* const* d_in, const int* in_sizes, int n_in,
                              void* d_out, int out_size, void* d_ws, size_t ws_size,
                              hipStream_t stream) {
    const float* x = (const float*)d_in[0];
    const float* W = (const float*)d_in[1];
    const float* b = (const float*)d_in[2];

    const int N = in_sizes[0] / D_MODEL;   // 32768

    float* o        = (float*)d_out;
    float* out_mask = o;
    float* out_prob = o + (size_t)N * N_EXP;
    float* out_imp  = out_prob + (size_t)N * N_EXP;
    float* out_load = out_imp + N_EXP;

    unsigned short* wt = (unsigned short*)d_ws;   // 3 planes * 64*2048 * 2B = 768 KB
    float* pws = (float*)((char*)d_ws
                 + (size_t)3 * N_EXP * D_MODEL * sizeof(unsigned short));

    wprep_kernel<<<128, 256, 0, stream>>>(W, wt);
    fused_kernel<<<N / ROWS, 256, 0, stream>>>(x, wt, b, out_mask, out_prob, pws);
    reduce_kernel<<<N_EXP, 256, 0, stream>>>(pws, out_imp, out_load);
}

// Round 5
// 478.968 us; speedup vs baseline: 1.0759x; 1.0759x over previous
//
#include <hip/hip_runtime.h>

// MoE Router (Switch) — R9: streaming-first MFMA.
// logits = x@W + b; top-3 one-hot mask; softmax probs; importance = load = col-sum.
// x: [N=32768, D=2048] f32, W: [D, E=64] f32, b: [E] f32.
// out = [mask (N*E) | prob (N*E) | importance (E) | load (E)]  (f32)
//
// R8 post-mortem: all pipes idle (VALU 11%, MFMA 8%, HBM 8%), 6 waves/CU.
// Invariant across R4-R8: x streams at only ~1.3 TB/s. Diagnosis: load-path
// latency/fill-bound — (1) too few waves, (2) every VMEM instr touched 16
// rows at pow2 stride (8KB x / 4KB wt) -> L1 set-aliasing, 16-segment fills.
// R9:
//   * grid 1024 x 256thr (4 waves), 4 blocks/CU -> 16 waves/CU.
//   * x staged to LDS; each staging instr reads 1KB CONTIGUOUS from one row.
//   * wave = expert quarter (16 experts, 3 planes), 2 row-tiles of 16 rows.
//     No split-K combine. Per 32-k substep: 3 wt global loads (double-buffered)
//     + 4 ds_read_b128 + 12 MFMA.
//   * wt planes padded to pitch 2080 (non-pow2) by wprep.
//   * Epilogue/reduce: R8-VERIFIED logic re-indexed (top3 insertion, merge12,
//     softmax, LDS-bounce stores, deterministic pws reduce).

#define D_MODEL 2048
#define N_EXP   64
#define BK      128
#define NCH     (D_MODEL / BK)    // 16
#define SUBS    (BK / 32)         // 4
#define TSTEPS  (NCH * SUBS)      // 64
#define ROWS    32
#define NBLK    1024              // 32768 / 32
#define XP      136               // x LDS pitch (floats): 16B-aligned rows
#define LP      68                // logit park pitch
#define WTP     2080              // wt plane pitch (elems) — non-pow2, 16B-aligned
#define PLANE   ((size_t)N_EXP * WTP)

typedef short bf16x8 __attribute__((ext_vector_type(8)));
typedef float f32x4  __attribute__((ext_vector_type(4)));

__device__ __forceinline__ unsigned short f32_bf16(float f) {
    unsigned u = __float_as_uint(f);
    return (unsigned short)((u + 0x7FFFu + ((u >> 16) & 1u)) >> 16);  // RNE
}
__device__ __forceinline__ float bf16_f32(unsigned short h) {
    return __uint_as_float((unsigned)h << 16);
}

// ---- W prep: split + transpose -> Wt_p[64][WTP] bf16, p = 0,1,2 ----
__global__ __launch_bounds__(256) void wprep_kernel(
    const float* __restrict__ W, unsigned short* __restrict__ wt) {
    const int gid = blockIdx.x * 256 + threadIdx.x;   // 32768 threads
    const int k   = gid & (D_MODEL - 1);
    const int e4  = gid >> 11;                        // 0..15
    const float4 w = *(const float4*)(W + (size_t)k * N_EXP + e4 * 4);
    unsigned short* p1 = wt;
    unsigned short* p2 = wt + PLANE;
    unsigned short* p3 = wt + 2 * PLANE;
#pragma unroll
    for (int j = 0; j < 4; ++j) {
        const float xv = ((const float*)&w)[j];
        const unsigned short h1 = f32_bf16(xv); const float f1 = bf16_f32(h1);
        const float r1 = xv - f1;
        const unsigned short h2 = f32_bf16(r1); const float f2 = bf16_f32(h2);
        const unsigned short h3 = f32_bf16(r1 - f2);
        const size_t o = (size_t)(e4 * 4 + j) * WTP + k;  // transposed, padded
        p1[o] = h1; p2[o] = h2; p3[o] = h3;
    }
}

__device__ __forceinline__ void bsplit8(const float4& xa, const float4& xb,
                                        bf16x8& h1, bf16x8& h2, bf16x8& h3) {
#pragma unroll
    for (int i = 0; i < 8; ++i) {
        const float xv = (i < 4) ? ((const float*)&xa)[i]
                                 : ((const float*)&xb)[i - 4];
        const unsigned short a1 = f32_bf16(xv); const float f1 = bf16_f32(a1);
        const float r1 = xv - f1;
        const unsigned short a2 = f32_bf16(r1); const float f2 = bf16_f32(a2);
        const unsigned short a3 = f32_bf16(r1 - f2);
        h1[i] = (short)a1; h2[i] = (short)a2; h3[i] = (short)a3;
    }
}

// ---- fused: GEMM (MFMA) + top-3 + softmax + partial col-sums ----
__global__ __launch_bounds__(256, 4) void fused_kernel(
    const float* __restrict__ x, const unsigned short* __restrict__ wt,
    const float* __restrict__ b,
    float* __restrict__ out_mask, float* __restrict__ out_prob,
    float* __restrict__ pws) {

    __shared__ float smem[5632];   // 22528 B; Xs[32][136] / epilogue time-share

    const int tid  = threadIdx.x;
    const int lane = tid & 63;
    const int wq   = __builtin_amdgcn_readfirstlane(tid >> 6);  // expert quarter
    const int n    = lane & 15;       // A row-in-tile / B expert-in-tile
    const int g    = lane >> 4;       // k-group
    const int rg   = blockIdx.x;
    const int e0   = wq * 16;

    // --- x staging: wave wq loads rows wq*8 + u*2 + (lane>>5); 1KB/instr ---
    const int srow = wq * 8 + (lane >> 5);
    const int scol = (lane & 31) * 4;
    const float* xs_src = x + (size_t)(rg * ROWS + srow) * D_MODEL + scol;
    float*       xs_dst = smem + srow * XP + scol;

    // --- wt per-lane pointers: expert e0+n, k-offset 8g, padded pitch ---
    const unsigned short* bpp0 = wt + 0 * PLANE + (size_t)(e0 + n) * WTP + 8 * g;
    const unsigned short* bpp1 = wt + 1 * PLANE + (size_t)(e0 + n) * WTP + 8 * g;
    const unsigned short* bpp2 = wt + 2 * PLANE + (size_t)(e0 + n) * WTP + 8 * g;

    const float bias = b[e0 + n];

    f32x4 acc0, acc1;
#pragma unroll
    for (int j = 0; j < 4; ++j) { acc0[j] = 0.0f; acc1[j] = 0.0f; }

    float4 tmp[4];
#pragma unroll
    for (int u = 0; u < 4; ++u)
        tmp[u] = *(const float4*)(xs_src + (size_t)(u * 2) * D_MODEL);

    bf16x8 w0 = *(const bf16x8*)(bpp0);      // t = 0
    bf16x8 w1 = *(const bf16x8*)(bpp1);
    bf16x8 w2 = *(const bf16x8*)(bpp2);

    for (int c = 0; c < NCH; ++c) {
        __syncthreads();                     // prev chunk fully consumed
#pragma unroll
        for (int u = 0; u < 4; ++u)
            *(float4*)(xs_dst + u * 2 * XP) = tmp[u];
        __syncthreads();
        const int cn = (c + 1 < NCH) ? c + 1 : c;   // clamp (redundant tail ok)
#pragma unroll
        for (int u = 0; u < 4; ++u)
            tmp[u] = *(const float4*)(xs_src + (size_t)(u * 2) * D_MODEL
                                      + cn * BK);
#pragma unroll
        for (int s = 0; s < SUBS; ++s) {
            const int t  = c * SUBS + s;
            const int tn = (t + 1 < TSTEPS) ? t + 1 : t;
            // prefetch next substep's wt fragments (global, L2-resident)
            const bf16x8 nw0 = *(const bf16x8*)(bpp0 + tn * 32);
            const bf16x8 nw1 = *(const bf16x8*)(bpp1 + tn * 32);
            const bf16x8 nw2 = *(const bf16x8*)(bpp2 + tn * 32);

            // row-tile 0
            {
                const float4 xa = *(const float4*)&smem[n * XP + s * 32 + 8 * g];
                const float4 xb = *(const float4*)&smem[n * XP + s * 32 + 8 * g + 4];
                bf16x8 h1, h2, h3;
                bsplit8(xa, xb, h1, h2, h3);
                acc0 = __builtin_amdgcn_mfma_f32_16x16x32_bf16(h1, w0, acc0, 0, 0, 0);
                acc0 = __builtin_amdgcn_mfma_f32_16x16x32_bf16(h1, w1, acc0, 0, 0, 0);
                acc0 = __builtin_amdgcn_mfma_f32_16x16x32_bf16(h1, w2, acc0, 0, 0, 0);
                acc0 = __builtin_amdgcn_mfma_f32_16x16x32_bf16(h2, w0, acc0, 0, 0, 0);
                acc0 = __builtin_amdgcn_mfma_f32_16x16x32_bf16(h2, w1, acc0, 0, 0, 0);
                acc0 = __builtin_amdgcn_mfma_f32_16x16x32_bf16(h3, w0, acc0, 0, 0, 0);
            }
            // row-tile 1 (rows +16)
            {
                const float4 xa = *(const float4*)&smem[(16 + n) * XP + s * 32 + 8 * g];
                const float4 xb = *(const float4*)&smem[(16 + n) * XP + s * 32 + 8 * g + 4];
                bf16x8 h1, h2, h3;
                bsplit8(xa, xb, h1, h2, h3);
                acc1 = __builtin_amdgcn_mfma_f32_16x16x32_bf16(h1, w0, acc1, 0, 0, 0);
                acc1 = __builtin_amdgcn_mfma_f32_16x16x32_bf16(h1, w1, acc1, 0, 0, 0);
                acc1 = __builtin_amdgcn_mfma_f32_16x16x32_bf16(h1, w2, acc1, 0, 0, 0);
                acc1 = __builtin_amdgcn_mfma_f32_16x16x32_bf16(h2, w0, acc1, 0, 0, 0);
                acc1 = __builtin_amdgcn_mfma_f32_16x16x32_bf16(h2, w1, acc1, 0, 0, 0);
                acc1 = __builtin_amdgcn_mfma_f32_16x16x32_bf16(h3, w0, acc1, 0, 0, 0);
            }
            w0 = nw0; w1 = nw1; w2 = nw2;
        }
    }

    __syncthreads();   // sync1: Xs reads done -> smem reusable for epilogue

    float* lgt = smem;           // [32][68] logits -> probs
    float* msk = smem + 2176;    // [32][68] mask bounce
    float* cnd = smem + 4352;    // [128][8] top-3 candidates
    float* ess = smem + 5376;    // [128]    exp partial sums

    // park: C/D layout (R8-verified): row = rt*16 + 4g + j, col = e0 + n
#pragma unroll
    for (int j = 0; j < 4; ++j) {
        lgt[( 0 + 4 * g + j) * LP + e0 + n] = acc0[j] + bias;
        lgt[(16 + 4 * g + j) * LP + e0 + n] = acc1[j] + bias;
    }
    __syncthreads();   // sync2

    const int q   = tid >> 5;     // 0..3 (expert quarter) for tid<128
    const int row = tid & 31;

    float v[16], pe[16];
    float x1 = 0.0f; int i1 = -1, i2 = -1, i3 = -1;

    if (tid < 128) {
#pragma unroll
        for (int i = 0; i < 16; ++i) v[i] = lgt[row * LP + q * 16 + i];

        // per-lane top-3 of 16 (ascending scan, strict > = lowest-index ties)
        float t1 = -INFINITY, t2 = -INFINITY, t3 = -INFINITY;
        int   j1 = 0, j2 = 0, j3 = 0;
#pragma unroll
        for (int e = 0; e < 16; ++e) {
            const float xv = v[e]; const int ge = q * 16 + e;
            if (xv > t1)      { t3 = t2; j3 = j2; t2 = t1; j2 = j1; t1 = xv; j1 = ge; }
            else if (xv > t2) { t3 = t2; j3 = j2; t2 = xv; j2 = ge; }
            else if (xv > t3) { t3 = xv; j3 = ge; }
        }
        float* cp = &cnd[(q * 32 + row) * 8];
        cp[0] = t1; cp[1] = __int_as_float(j1);
        cp[2] = t2; cp[3] = __int_as_float(j2);
        cp[4] = t3; cp[5] = __int_as_float(j3);
    }
    __syncthreads();   // sync3

    if (tid < 128) {
        // merge 4 quarters x 3 candidates (quarter-ascending = e-ascending)
        float bv[12]; int bg[12];
#pragma unroll
        for (int w = 0; w < 4; ++w) {
            const float* cp = &cnd[(w * 32 + row) * 8];
#pragma unroll
            for (int k = 0; k < 3; ++k) {
                bv[w * 3 + k] = cp[2 * k];
                bg[w * 3 + k] = __float_as_int(cp[2 * k + 1]);
            }
        }
#pragma unroll
        for (int pick = 0; pick < 3; ++pick) {
            float mv = bv[0]; int mg = bg[0]; int mk = 0;
#pragma unroll
            for (int k = 1; k < 12; ++k)
                if (bv[k] > mv) { mv = bv[k]; mg = bg[k]; mk = k; }
            if (pick == 0)      { x1 = mv; i1 = mg; }
            else if (pick == 1) { i2 = mg; }
            else                { i3 = mg; }
#pragma unroll
            for (int k = 0; k < 12; ++k)
                if (k == mk) bv[k] = -INFINITY;   // static index: stays in regs
        }

        float es = 0.0f;
#pragma unroll
        for (int i = 0; i < 16; ++i) { pe[i] = __expf(v[i] - x1); es += pe[i]; }
        ess[q * 32 + row] = es;
    }
    __syncthreads();   // sync4

    if (tid < 128) {
        const float s = ess[row] + ess[32 + row] + ess[64 + row] + ess[96 + row];
        const float sinv = 1.0f / s;
#pragma unroll
        for (int i = 0; i < 16; ++i) {
            const float pr = pe[i] * sinv;
            const int ge = q * 16 + i;
            lgt[row * LP + ge] = pr;                      // probs overwrite logits
            msk[row * LP + ge] =
                (ge == i1 || ge == i2 || ge == i3) ? 1.0f : 0.0f;
            // column sum over the 32 rows (lanes of this 32-group)
            float se = pr;
#pragma unroll
            for (int m = 1; m <= 16; m <<= 1) se += __shfl_xor(se, m);
            if ((tid & 31) == 0)
                pws[(size_t)ge * NBLK + rg] = se;
        }
    }
    __syncthreads();   // sync5

    // coalesced stores via LDS bounce: 512 float4 per array, 2 per thread
    const size_t obase = (size_t)rg * (ROWS * N_EXP);
#pragma unroll
    for (int u = 0; u < 2; ++u) {
        const int f  = tid + u * 256;       // 0..511
        const int r  = f >> 4;
        const int c4 = f & 15;
        *(float4*)(out_prob + obase + (size_t)f * 4) =
            *(const float4*)&lgt[r * LP + c4 * 4];
        *(float4*)(out_mask + obase + (size_t)f * 4) =
            *(const float4*)&msk[r * LP + c4 * 4];
    }
}

// one block per expert: sum its NBLK contiguous partials -> imp[e], load[e]
__global__ __launch_bounds__(256) void reduce_kernel(
    const float* __restrict__ pws,
    float* __restrict__ out_imp, float* __restrict__ out_load) {

    __shared__ float red[4];
    const int e   = blockIdx.x;
    const int tid = threadIdx.x;

    const float* p = pws + (size_t)e * NBLK;
    float s = p[tid] + p[tid + 256] + p[tid + 512] + p[tid + 768];

#pragma unroll
    for (int m = 32; m > 0; m >>= 1) s += __shfl_xor(s, m);
    if ((tid & 63) == 0) red[tid >> 6] = s;
    __syncthreads();
    if (tid == 0) {
        const float t = red[0] + red[1] + red[2] + red[3];
        out_imp[e]  = t;
        out_load[e] = t;
    }
}

extern "C" void kernel_launch(void* const* d_in, const int* in_sizes, int n_in,
                              void* d_out, int out_size, void* d_ws, size_t ws_size,
                              hipStream_t stream) {
    const float* x = (const float*)d_in[0];
    const float* W = (const float*)d_in[1];
    const float* b = (const float*)d_in[2];

    const int N = in_sizes[0] / D_MODEL;   // 32768

    float* o        = (float*)d_out;
    float* out_mask = o;
    float* out_prob = o + (size_t)N * N_EXP;
    float* out_imp  = out_prob + (size_t)N * N_EXP;
    float* out_load = out_imp + N_EXP;

    unsigned short* wt = (unsigned short*)d_ws;   // 3 * 64 * 2080 * 2B = 780 KB
    float* pws = (float*)((char*)d_ws + 3 * PLANE * sizeof(unsigned short));

    wprep_kernel<<<128, 256, 0, stream>>>(W, wt);
    fused_kernel<<<N / ROWS, 256, 0, stream>>>(x, wt, b, out_mask, out_prob, pws);
    reduce_kernel<<<N_EXP, 256, 0, stream>>>(pws, out_imp, out_load);
}